// Round 1
// 300.387 us; speedup vs baseline: 1.0885x; 1.0885x over previous
//
#include <hip/hip_runtime.h>

typedef short v8s __attribute__((ext_vector_type(8)));
typedef float v4f __attribute__((ext_vector_type(4)));

__device__ __forceinline__ short f2bf(float f) {
  union { float f; unsigned u; } v; v.f = f;
  unsigned r = v.u + 0x7FFFu + ((v.u >> 16) & 1u);
  return (short)(r >> 16);
}

// async global->LDS, 16B per lane; LDS dst = wave-uniform base + lane*16
__device__ __forceinline__ void gll16(const short* g, short* l) {
  __builtin_amdgcn_global_load_lds(
      (const __attribute__((address_space(1))) void*)g,
      (__attribute__((address_space(3))) void*)l, 16, 0, 0);
}

// ---------------- elementwise cast x: fp32 -> bf16 ----------------
__global__ void cast_f32_bf16(const float* __restrict__ in, short* __restrict__ out, int n4) {
  int i = blockIdx.x * blockDim.x + threadIdx.x;
  if (i >= n4) return;
  float4 v = ((const float4*)in)[i];
  short4 o;
  o.x = f2bf(v.x); o.y = f2bf(v.y); o.z = f2bf(v.z); o.w = f2bf(v.w);
  ((short4*)out)[i] = o;
}

// ---------------- all weight transposes in one launch ----------------
__global__ void cast_transpose_weights(const float* __restrict__ Wq, const float* __restrict__ Wk,
                                       const float* __restrict__ Wv, const float* __restrict__ Wo,
                                       short* __restrict__ Wqkvt, short* __restrict__ Wot) {
  __shared__ float tile[32][33];
  const int tx = threadIdx.x, ty = threadIdx.y;
  int bx = blockIdx.x;
  const float* src; short* dst; int C, cb;
  if (bx < 64)      { src = Wq; dst = Wqkvt;                        C = 2048; cb = bx; }
  else if (bx < 80) { src = Wk; dst = Wqkvt + (size_t)2048 * 2048;  C = 512;  cb = bx - 64; }
  else if (bx < 96) { src = Wv; dst = Wqkvt + (size_t)2560 * 2048;  C = 512;  cb = bx - 80; }
  else              { src = Wo; dst = Wot;                          C = 2048; cb = bx - 96; }
  const int c0 = cb * 32, r0 = blockIdx.y * 32;
#pragma unroll
  for (int i = 0; i < 4; ++i)
    tile[ty + 8 * i][tx] = src[(size_t)(r0 + ty + 8 * i) * C + c0 + tx];
  __syncthreads();
#pragma unroll
  for (int i = 0; i < 4; ++i)
    dst[(size_t)(c0 + ty + 8 * i) * 2048 + r0 + tx] = f2bf(tile[tx][ty + 8 * i]);
}

// ---------------- V transpose + key-permute out of packed QKV ----------------
// key perm (within each 32-key block): k -> (k&~31) | q4*8 | hi*4 | r,
// q4=(k>>2)&3, hi=(k>>4)&1, r=k&3.  Aligns PV A-frag packing with S^T C-layout.
__global__ void transpose_v_perm(const short* __restrict__ qkv, short* __restrict__ out) {
  __shared__ short tile[32][33];
  const int tx = threadIdx.x, ty = threadIdx.y;
  const int c0 = blockIdx.x * 32, r0 = blockIdx.y * 32;
  const int z = blockIdx.z;
#pragma unroll
  for (int i = 0; i < 4; ++i)
    tile[ty + 8 * i][tx] = qkv[(size_t)(z * 2048 + r0 + ty + 8 * i) * 3072 + 2560 + c0 + tx];
  __syncthreads();
#pragma unroll
  for (int i = 0; i < 4; ++i) {
    int k = r0 + tx;
    int pk = (k & ~31) | ((((k >> 2) & 3) * 2 + ((k >> 4) & 1)) * 4) | (k & 3);
    out[(size_t)z * 512 * 2048 + (size_t)(c0 + ty + 8 * i) * 2048 + pk] = tile[tx][ty + 8 * i];
  }
}

// ---------------- GEMM: C[M][N] = A[M][K] @ Bt[N][K]^T  (bf16 in) ----------------
template <int BF16_OUT>
__global__ __launch_bounds__(256) void gemm_bt(const short* __restrict__ A,
                                               const short* __restrict__ Bt,
                                               void* __restrict__ Cout,
                                               const float* __restrict__ bias,
                                               int M, int N, int K) {
  __shared__ short As[128 * 32];
  __shared__ short Bs[128 * 32];
  const int tid = threadIdx.x;
  const int m0 = blockIdx.y * 128, n0 = blockIdx.x * 128;
  const int w = tid >> 6, lane = tid & 63, quad = lane >> 4, l16 = lane & 15;
  const int wm = (w >> 1) * 64, wn = (w & 1) * 64;
  v4f acc[4][4] = {};
  const int srow = lane >> 2, scol = (lane & 3) * 8;
  const short* Ap = A + (size_t)(m0 + w * 32 + srow) * K + scol;
  const short* Bp = Bt + (size_t)(n0 + w * 32 + srow) * K + scol;
  short* AsW = &As[(w * 32) * 32 + lane * 8];
  short* BsW = &Bs[(w * 32) * 32 + lane * 8];
  const size_t rstep = (size_t)16 * K;
  for (int k0 = 0; k0 < K; k0 += 32) {
    __syncthreads();
    gll16(Ap, AsW);
    gll16(Ap + rstep, AsW + 16 * 32);
    gll16(Bp, BsW);
    gll16(Bp + rstep, BsW + 16 * 32);
    __syncthreads();
    Ap += 32; Bp += 32;
    v8s af[4], bf[4];
#pragma unroll
    for (int i = 0; i < 4; ++i) af[i] = *(const v8s*)&As[(wm + i * 16 + l16) * 32 + quad * 8];
#pragma unroll
    for (int i = 0; i < 4; ++i) bf[i] = *(const v8s*)&Bs[(wn + i * 16 + l16) * 32 + quad * 8];
#pragma unroll
    for (int mi = 0; mi < 4; ++mi)
#pragma unroll
      for (int ni = 0; ni < 4; ++ni)
        acc[mi][ni] = __builtin_amdgcn_mfma_f32_16x16x32_bf16(af[mi], bf[ni], acc[mi][ni], 0, 0, 0);
  }
#pragma unroll
  for (int mi = 0; mi < 4; ++mi) {
#pragma unroll
    for (int ni = 0; ni < 4; ++ni) {
      const int col = n0 + wn + ni * 16 + l16;
#pragma unroll
      for (int r = 0; r < 4; ++r) {
        const int row = m0 + wm + mi * 16 + quad * 4 + r;
        if (BF16_OUT) {
          ((short*)Cout)[(size_t)row * N + col] = f2bf(acc[mi][ni][r]);
        } else {
          ((float*)Cout)[(size_t)row * N + col] = acc[mi][ni][r] + bias[col];
        }
      }
    }
  }
}

// ---------------- flash attention v5 ----------------
// grid (16, 32): block = paired 64-row q-tiles (qt=bx, 31-bx) -> uniform 33 ktiles.
// 512 blocks / 256 CUs = 2 blocks/CU = 8 waves/CU = 2 waves/SIMD (was 1 with 128-row
// tiles and grid 256). Independent blocks overlap MFMA with softmax/stage latency.
// 4 waves in 2x2 (wq: 32 q-rows, wk: 32 keys). Double-buffered LDS + async gll16
// prefetch issued a full compute-phase before its drain. o/l summed across wk at
// epilogue via LDS.
__global__ __launch_bounds__(256, 2) void flash_attn4(const short* __restrict__ QKV,
                                                      const short* __restrict__ Vtb,
                                                      short* __restrict__ ctx) {
  __shared__ __align__(16) short smem[32768];  // 2 x (Ks 8192 + Vs 8192); epilogue overlay
  const int tid = threadIdx.x;
  const int w = tid >> 6, lane = tid & 63, quad = lane >> 4, l16 = lane & 15;
  const int wq = w >> 1, wk = w & 1;
  const int bh = blockIdx.y;
  const int b = bh >> 4, h = bh & 15, g = h >> 2;
  const float scale = 0.08838834764831845f;
  v8s ones;
#pragma unroll
  for (int i = 0; i < 8; ++i) ones[i] = (short)0x3F80;

  // staging lane roles (wave stages K rows w*16..+15, V d-rows w*32..+31)
  const int krl = lane >> 4, kcl = lane & 15;
  const int vrl = lane >> 3, vcl = lane & 7;
  const short* Kg0 = QKV + (size_t)(b * 2048 + w * 16 + krl) * 3072 + 2048 + g * 128;
  const short* Vg0 = Vtb + (size_t)(b * 512 + g * 128 + w * 32 + vrl) * 2048 + (vcl ^ (vrl & 7)) * 8;
  short* kd = smem + (w * 16) * 128 + lane * 8;
  short* vd = smem + 8192 + (w * 32) * 64 + lane * 8;

  auto stage = [&](int key0, int bs) {
    const short* kg = Kg0 + (size_t)key0 * 3072;
    const short* vg = Vg0 + key0;
#pragma unroll
    for (int ii = 0; ii < 4; ++ii) {
      const int rl = (ii * 4 + krl) & 15;
      gll16(kg + (size_t)(ii * 4) * 3072 + (kcl ^ rl) * 8, kd + bs * 16384 + ii * 512);
      gll16(vg + (size_t)(ii * 8) * 2048, vd + bs * 16384 + ii * 512);
    }
  };

  float* red = (float*)smem;

#pragma unroll 1
  for (int half = 0; half < 2; ++half) {
    const int qt = half ? (31 - blockIdx.x) : blockIdx.x;
    const int q0 = qt * 64;
    const int qb = q0 + wq * 32;

    // Q fragments: 2 qsets of 16 rows (serve as MFMA B-operand for S^T = K*Q^T)
    v8s aq[2][4];
#pragma unroll
    for (int qs = 0; qs < 2; ++qs) {
      const short* Qp = QKV + (size_t)(b * 2048 + qb + qs * 16 + l16) * 3072 + h * 128 + quad * 8;
#pragma unroll
      for (int kk = 0; kk < 4; ++kk) aq[qs][kk] = *(const v8s*)(Qp + kk * 32);
    }
    v4f o[2][8] = {};
    v4f ol[2] = {};

    __syncthreads();            // protect smem from previous half's epilogue readers
    stage(0, 0);
    const int nk = qt + 1;
#pragma unroll 1
    for (int kt = 0; kt < nk; ++kt) {
      const int key0 = kt << 6;
      __syncthreads();          // drains stage(kt) [vmcnt(0)], orders buffer reuse
      if (kt + 1 < nk) stage((kt + 1) << 6, (kt + 1) & 1);
      const short* Ks = smem + (kt & 1) * 16384;
      const short* Vs = Ks + 8192;
      const int kb = key0 + wk * 32;
      if (kb > qb + 31) continue;  // wave-uniform: fully masked
      // S^T = K @ Q^T for this wave's 32 keys x 32 q
      v4f sf[2][2] = {};
#pragma unroll
      for (int kfl = 0; kfl < 2; ++kfl)
#pragma unroll
        for (int kk = 0; kk < 4; ++kk) {
          v8s kfr = *(const v8s*)&Ks[((wk * 2 + kfl) * 16 + l16) * 128 + (((kk * 4 + quad) ^ l16) * 8)];
#pragma unroll
          for (int qs = 0; qs < 2; ++qs)
            sf[qs][kfl] = __builtin_amdgcn_mfma_f32_16x16x32_bf16(kfr, aq[qs][kk], sf[qs][kfl], 0, 0, 0);
        }
      // mask + exp + pack P^T C-layout -> PV A-frag (32 keys)
      const bool diag = (kb + 31 > qb);
      v8s pa[2];
#pragma unroll
      for (int qs = 0; qs < 2; ++qs) {
        const int qg = qb + qs * 16 + l16;
        v8s t;
#pragma unroll
        for (int kfl = 0; kfl < 2; ++kfl)
#pragma unroll
          for (int r = 0; r < 4; ++r) {
            float s = sf[qs][kfl][r] * scale;
            if (diag && (kb + kfl * 16 + quad * 4 + r > qg)) s = -1e30f;
            t[kfl * 4 + r] = f2bf(__expf(s));
          }
        pa[qs] = t;
      }
      // O += P @ V ; l += P @ 1
#pragma unroll
      for (int nf = 0; nf < 8; ++nf) {
        v8s vf = *(const v8s*)&Vs[(nf * 16 + l16) * 64 + (((wk * 4 + quad) ^ (l16 & 7)) * 8)];
#pragma unroll
        for (int qs = 0; qs < 2; ++qs)
          o[qs][nf] = __builtin_amdgcn_mfma_f32_16x16x32_bf16(pa[qs], vf, o[qs][nf], 0, 0, 0);
      }
#pragma unroll
      for (int qs = 0; qs < 2; ++qs)
        ol[qs] = __builtin_amdgcn_mfma_f32_16x16x32_bf16(pa[qs], ones, ol[qs], 0, 0, 0);
    }
    __syncthreads();   // all LDS reads of K/V done; smem becomes reduction buffer

    // ---- epilogue: sum o/l across the wk pair, normalize, store ----
    // phase A: l
    if (wk == 1) {
#pragma unroll
      for (int qs = 0; qs < 2; ++qs)
        *(v4f*)&red[(wq * 2 + qs) * 256 + l16 * 16 + quad * 4] = ol[qs];
    }
    __syncthreads();
    if (wk == 0) {
#pragma unroll
      for (int qs = 0; qs < 2; ++qs)
        ol[qs] += *(const v4f*)&red[(wq * 2 + qs) * 256 + l16 * 16 + quad * 4];
    }
    __syncthreads();
    // phase B: o
    if (wk == 1) {
#pragma unroll
      for (int qs = 0; qs < 2; ++qs)
#pragma unroll
        for (int nf = 0; nf < 8; ++nf)
          *(v4f*)&red[(((wq * 2 + qs) * 8 + nf) * 256) + l16 * 16 + quad * 4] = o[qs][nf];
    }
    __syncthreads();
    if (wk == 0) {
#pragma unroll
      for (int qs = 0; qs < 2; ++qs) {
        float inv[4];
#pragma unroll
        for (int r = 0; r < 4; ++r) inv[r] = 1.0f / ol[qs][r];
#pragma unroll
        for (int nf = 0; nf < 8; ++nf) {
          v4f osum = o[qs][nf] + *(const v4f*)&red[(((wq * 2 + qs) * 8 + nf) * 256) + l16 * 16 + quad * 4];
#pragma unroll
          for (int r = 0; r < 4; ++r) {
            const int row = qb + qs * 16 + quad * 4 + r;
            ctx[(size_t)(b * 2048 + row) * 2048 + h * 128 + nf * 16 + l16] = f2bf(osum[r] * inv[r]);
          }
        }
      }
    }
  }
}

extern "C" void kernel_launch(void* const* d_in, const int* in_sizes, int n_in,
                              void* d_out, int out_size, void* d_ws, size_t ws_size,
                              hipStream_t stream) {
  const float* x = (const float*)d_in[0];
  const float* Wq = (const float*)d_in[1];
  const float* Wk = (const float*)d_in[2];
  const float* Wv = (const float*)d_in[3];
  const float* Wo = (const float*)d_in[4];
  const float* bo = (const float*)d_in[5];
  float* out = (float*)d_out;
  char* ws = (char*)d_ws;

  // workspace layout (bytes), total 64 MiB; ctx aliases xb
  short* xb    = (short*)(ws);             // 16,777,216  x bf16 [4096][2048]
  short* ctx   = (short*)(ws);             // alias       [4096][2048]
  short* Wqkvt = (short*)(ws + 16777216);  // 12,582,912  [3072 n][2048 k] packed Q|K|V
  short* Wot   = (short*)(ws + 29360128);  //  8,388,608  [2048 n][2048 k]
  short* QKV   = (short*)(ws + 37748736);  // 25,165,824  [4096][3072]
  short* Vtb   = (short*)(ws + 62914560);  //  4,194,304  [b][512][2048] key-permuted

  dim3 tb(32, 8);
  cast_f32_bf16<<<8192, 256, 0, stream>>>(x, xb, 2097152);
  cast_transpose_weights<<<dim3(160, 64), tb, 0, stream>>>(Wq, Wk, Wv, Wo, Wqkvt, Wot);

  gemm_bt<1><<<dim3(24, 32), 256, 0, stream>>>(xb, Wqkvt, (void*)QKV, nullptr, 4096, 3072, 2048);

  transpose_v_perm<<<dim3(16, 64, 2), tb, 0, stream>>>(QKV, Vtb);

  flash_attn4<<<dim3(16, 32), 256, 0, stream>>>(QKV, Vtb, ctx);

  gemm_bt<0><<<dim3(16, 32), 256, 0, stream>>>(ctx, Wot, (void*)out, bo, 4096, 2048, 2048);
}

// Round 4
// 288.921 us; speedup vs baseline: 1.1317x; 1.0397x over previous
//
#include <hip/hip_runtime.h>

typedef short v8s __attribute__((ext_vector_type(8)));
typedef float v4f __attribute__((ext_vector_type(4)));

__device__ __forceinline__ short f2bf(float f) {
  union { float f; unsigned u; } v; v.f = f;
  unsigned r = v.u + 0x7FFFu + ((v.u >> 16) & 1u);
  return (short)(r >> 16);
}

// async global->LDS, 16B per lane; LDS dst = wave-uniform base + lane*16
__device__ __forceinline__ void gll16(const short* g, short* l) {
  __builtin_amdgcn_global_load_lds(
      (const __attribute__((address_space(1))) void*)g,
      (__attribute__((address_space(3))) void*)l, 16, 0, 0);
}

// ---------------- merged: x cast (blocks 0..8191) + weight transposes ----------------
__global__ void cast_and_transpose(const float* __restrict__ x, short* __restrict__ xb,
                                   const float* __restrict__ Wq, const float* __restrict__ Wk,
                                   const float* __restrict__ Wv, const float* __restrict__ Wo,
                                   short* __restrict__ Wqkvt, short* __restrict__ Wot) {
  const int tid = threadIdx.x;
  int bid = blockIdx.x;
  if (bid < 8192) {
    int i = bid * 256 + tid;
    float4 v = ((const float4*)x)[i];
    short4 o;
    o.x = f2bf(v.x); o.y = f2bf(v.y); o.z = f2bf(v.z); o.w = f2bf(v.w);
    ((short4*)xb)[i] = o;
    return;
  }
  __shared__ float tile[32][33];
  bid -= 8192;
  const int tx = tid & 31, ty = tid >> 5;
  int bx = bid % 160;
  const int byy = bid / 160;
  const float* src; short* dst; int C, cb;
  if (bx < 64)      { src = Wq; dst = Wqkvt;                        C = 2048; cb = bx; }
  else if (bx < 80) { src = Wk; dst = Wqkvt + (size_t)2048 * 2048;  C = 512;  cb = bx - 64; }
  else if (bx < 96) { src = Wv; dst = Wqkvt + (size_t)2560 * 2048;  C = 512;  cb = bx - 80; }
  else              { src = Wo; dst = Wot;                          C = 2048; cb = bx - 96; }
  const int c0 = cb * 32, r0 = byy * 32;
#pragma unroll
  for (int i = 0; i < 4; ++i)
    tile[ty + 8 * i][tx] = src[(size_t)(r0 + ty + 8 * i) * C + c0 + tx];
  __syncthreads();
#pragma unroll
  for (int i = 0; i < 4; ++i)
    dst[(size_t)(c0 + ty + 8 * i) * 2048 + r0 + tx] = f2bf(tile[tx][ty + 8 * i]);
}

// ---------------- V transpose + key-permute out of packed QKV ----------------
__global__ void transpose_v_perm(const short* __restrict__ qkv, short* __restrict__ out) {
  __shared__ short tile[32][33];
  const int tx = threadIdx.x, ty = threadIdx.y;
  const int c0 = blockIdx.x * 32, r0 = blockIdx.y * 32;
  const int z = blockIdx.z;
#pragma unroll
  for (int i = 0; i < 4; ++i)
    tile[ty + 8 * i][tx] = qkv[(size_t)(z * 2048 + r0 + ty + 8 * i) * 3072 + 2560 + c0 + tx];
  __syncthreads();
#pragma unroll
  for (int i = 0; i < 4; ++i) {
    int k = r0 + tx;
    int pk = (k & ~31) | ((((k >> 2) & 3) * 2 + ((k >> 4) & 1)) * 4) | (k & 3);
    out[(size_t)z * 512 * 2048 + (size_t)(c0 + ty + 8 * i) * 2048 + pk] = tile[tx][ty + 8 * i];
  }
}

// ---------------- GEMM v2p: C[M][N] = A[M][K] @ Bt[N][K]^T (bf16 in) ----------------
// 128x128 tile, BK=32, double-buffered LDS (32 KiB), conventional 2-phase pipeline:
//   stage(t+1) -> ds_read+MFMA(buf t) -> __syncthreads   (one drain per K-step; stage
// latency hides under the 64-MFMA compute phase).  Only __syncthreads for sync — no
// raw-barrier/counted-vmcnt protocol (de-risked after 2 container failures).
// XOR chunk swizzle kills the 4-way ds_read_b128 bank conflict (6.3M cycles measured):
// stored slot (lane&3) of row r holds k-chunk slot^(r&3)^((r>>2)&3)  (involution;
// global source pre-swizzled, LDS dest linear as gll16 requires, read side applies
// the same XOR).  __launch_bounds__(256,3) -> 3 blocks/CU (QKV grid 768 = exactly 3/CU).
// Bijective XCD swizzle (grid = 8*cpx).
template <int BF16_OUT>
__global__ __launch_bounds__(256, 3) void gemm_bt2p(const short* __restrict__ A,
                                                    const short* __restrict__ Bt,
                                                    void* __restrict__ Cout,
                                                    const float* __restrict__ bias,
                                                    int N, int K, int nbx, int cpx) {
  __shared__ __align__(16) short sm[2 * 8192];  // 2 bufs x (A[128][32] | B[128][32])
  const int tid = threadIdx.x;
  const int w = tid >> 6, lane = tid & 63, quad = lane >> 4, l16 = lane & 15;
  const int wm = (w >> 1) * 64, wn = (w & 1) * 64;
  const int bid = blockIdx.x;
  const int swz = (bid & 7) * cpx + (bid >> 3);
  const int n0 = (swz % nbx) * 128, m0 = (swz / nbx) * 128;
  const int NT = K >> 5;

  // staging: wave w stages rows {w*16+srow, 64+w*16+srow} of A and B tiles.
  // global column chunk = slot ^ (srow&3) ^ ((srow>>2)&3), slot = lane&3.
  const int srow = lane >> 2;
  const int sc = ((lane & 3) ^ ((lane >> 2) & 3) ^ ((lane >> 4) & 3)) * 8;
  const short* Ag = A + (size_t)(m0 + w * 16 + srow) * K + sc;
  const short* Bg = Bt + (size_t)(n0 + w * 16 + srow) * K + sc;
  short* Ad = sm + w * 512 + lane * 8;
  short* Bd = sm + 4096 + w * 512 + lane * 8;
  const size_t rjump = (size_t)64 * K;

  auto stage = [&](int t, int bf_) {
    const int k = t << 5;
    short* ad = Ad + bf_ * 8192;
    short* bd = Bd + bf_ * 8192;
    gll16(Ag + k, ad);
    gll16(Ag + k + rjump, ad + 2048);
    gll16(Bg + k, bd);
    gll16(Bg + k + rjump, bd + 2048);
  };

  // frag reads: row = frag_base + l16; chunk `quad` lives at slot quad^(l16&3)^((l16>>2)&3)
  const int rsc = (quad ^ (l16 & 3) ^ ((l16 >> 2) & 3)) * 8;
  const short* aBase = sm + (wm + l16) * 32 + rsc;
  const short* bBase = sm + 4096 + (wn + l16) * 32 + rsc;

  v4f acc[4][4] = {};

  stage(0, 0);
  __syncthreads();

  for (int t = 0; t < NT; ++t) {
    if (t + 1 < NT) stage(t + 1, (t + 1) & 1);  // overlaps with this tile's compute
    const int bo_ = (t & 1) * 8192;
    v8s af[4], bf[4];
#pragma unroll
    for (int i = 0; i < 4; ++i) af[i] = *(const v8s*)(aBase + bo_ + i * 512);
#pragma unroll
    for (int i = 0; i < 4; ++i) bf[i] = *(const v8s*)(bBase + bo_ + i * 512);
    __builtin_amdgcn_s_setprio(1);
#pragma unroll
    for (int mi = 0; mi < 4; ++mi)
#pragma unroll
      for (int ni = 0; ni < 4; ++ni)
        acc[mi][ni] = __builtin_amdgcn_mfma_f32_16x16x32_bf16(af[mi], bf[ni], acc[mi][ni], 0, 0, 0);
    __builtin_amdgcn_s_setprio(0);
    if (t + 1 < NT) __syncthreads();  // drains stage(t+1); publishes buf (t+1)&1
  }

#pragma unroll
  for (int mi = 0; mi < 4; ++mi) {
#pragma unroll
    for (int ni = 0; ni < 4; ++ni) {
      const int col = n0 + wn + ni * 16 + l16;
#pragma unroll
      for (int r = 0; r < 4; ++r) {
        const int row = m0 + wm + mi * 16 + quad * 4 + r;
        if (BF16_OUT) {
          ((short*)Cout)[(size_t)row * N + col] = f2bf(acc[mi][ni][r]);
        } else {
          ((float*)Cout)[(size_t)row * N + col] = acc[mi][ni][r] + bias[col];
        }
      }
    }
  }
}

// ---------------- flash attention v5 ----------------
// grid (16, 32): paired 64-row q-tiles (qt=bx, 31-bx) -> uniform 33 ktiles; 2 blocks/CU.
// + setprio around MFMA clusters (T5).
__global__ __launch_bounds__(256, 2) void flash_attn4(const short* __restrict__ QKV,
                                                      const short* __restrict__ Vtb,
                                                      short* __restrict__ ctx) {
  __shared__ __align__(16) short smem[32768];  // 2 x (Ks 8192 + Vs 8192); epilogue overlay
  const int tid = threadIdx.x;
  const int w = tid >> 6, lane = tid & 63, quad = lane >> 4, l16 = lane & 15;
  const int wq = w >> 1, wk = w & 1;
  const int bh = blockIdx.y;
  const int b = bh >> 4, h = bh & 15, g = h >> 2;
  const float scale = 0.08838834764831845f;
  v8s ones;
#pragma unroll
  for (int i = 0; i < 8; ++i) ones[i] = (short)0x3F80;

  const int krl = lane >> 4, kcl = lane & 15;
  const int vrl = lane >> 3, vcl = lane & 7;
  const short* Kg0 = QKV + (size_t)(b * 2048 + w * 16 + krl) * 3072 + 2048 + g * 128;
  const short* Vg0 = Vtb + (size_t)(b * 512 + g * 128 + w * 32 + vrl) * 2048 + (vcl ^ (vrl & 7)) * 8;
  short* kd = smem + (w * 16) * 128 + lane * 8;
  short* vd = smem + 8192 + (w * 32) * 64 + lane * 8;

  auto stage = [&](int key0, int bs) {
    const short* kg = Kg0 + (size_t)key0 * 3072;
    const short* vg = Vg0 + key0;
#pragma unroll
    for (int ii = 0; ii < 4; ++ii) {
      const int rl = (ii * 4 + krl) & 15;
      gll16(kg + (size_t)(ii * 4) * 3072 + (kcl ^ rl) * 8, kd + bs * 16384 + ii * 512);
      gll16(vg + (size_t)(ii * 8) * 2048, vd + bs * 16384 + ii * 512);
    }
  };

  float* red = (float*)smem;

#pragma unroll 1
  for (int half = 0; half < 2; ++half) {
    const int qt = half ? (31 - blockIdx.x) : blockIdx.x;
    const int q0 = qt * 64;
    const int qb = q0 + wq * 32;

    v8s aq[2][4];
#pragma unroll
    for (int qs = 0; qs < 2; ++qs) {
      const short* Qp = QKV + (size_t)(b * 2048 + qb + qs * 16 + l16) * 3072 + h * 128 + quad * 8;
#pragma unroll
      for (int kk = 0; kk < 4; ++kk) aq[qs][kk] = *(const v8s*)(Qp + kk * 32);
    }
    v4f o[2][8] = {};
    v4f ol[2] = {};

    __syncthreads();            // protect smem from previous half's epilogue readers
    stage(0, 0);
    const int nk = qt + 1;
#pragma unroll 1
    for (int kt = 0; kt < nk; ++kt) {
      const int key0 = kt << 6;
      __syncthreads();          // drains stage(kt) [vmcnt(0)], orders buffer reuse
      if (kt + 1 < nk) stage((kt + 1) << 6, (kt + 1) & 1);
      const short* Ks = smem + (kt & 1) * 16384;
      const short* Vs = Ks + 8192;
      const int kb = key0 + wk * 32;
      if (kb > qb + 31) continue;  // wave-uniform: fully masked
      v4f sf[2][2] = {};
      __builtin_amdgcn_s_setprio(1);
#pragma unroll
      for (int kfl = 0; kfl < 2; ++kfl)
#pragma unroll
        for (int kk = 0; kk < 4; ++kk) {
          v8s kfr = *(const v8s*)&Ks[((wk * 2 + kfl) * 16 + l16) * 128 + (((kk * 4 + quad) ^ l16) * 8)];
#pragma unroll
          for (int qs = 0; qs < 2; ++qs)
            sf[qs][kfl] = __builtin_amdgcn_mfma_f32_16x16x32_bf16(kfr, aq[qs][kk], sf[qs][kfl], 0, 0, 0);
        }
      __builtin_amdgcn_s_setprio(0);
      const bool diag = (kb + 31 > qb);
      v8s pa[2];
#pragma unroll
      for (int qs = 0; qs < 2; ++qs) {
        const int qg = qb + qs * 16 + l16;
        v8s t;
#pragma unroll
        for (int kfl = 0; kfl < 2; ++kfl)
#pragma unroll
          for (int r = 0; r < 4; ++r) {
            float s = sf[qs][kfl][r] * scale;
            if (diag && (kb + kfl * 16 + quad * 4 + r > qg)) s = -1e30f;
            t[kfl * 4 + r] = f2bf(__expf(s));
          }
        pa[qs] = t;
      }
      __builtin_amdgcn_s_setprio(1);
#pragma unroll
      for (int nf = 0; nf < 8; ++nf) {
        v8s vf = *(const v8s*)&Vs[(nf * 16 + l16) * 64 + (((wk * 4 + quad) ^ (l16 & 7)) * 8)];
#pragma unroll
        for (int qs = 0; qs < 2; ++qs)
          o[qs][nf] = __builtin_amdgcn_mfma_f32_16x16x32_bf16(pa[qs], vf, o[qs][nf], 0, 0, 0);
      }
#pragma unroll
      for (int qs = 0; qs < 2; ++qs)
        ol[qs] = __builtin_amdgcn_mfma_f32_16x16x32_bf16(pa[qs], ones, ol[qs], 0, 0, 0);
      __builtin_amdgcn_s_setprio(0);
    }
    __syncthreads();   // all LDS reads of K/V done; smem becomes reduction buffer

    // ---- epilogue: sum o/l across the wk pair, normalize, store ----
    if (wk == 1) {
#pragma unroll
      for (int qs = 0; qs < 2; ++qs)
        *(v4f*)&red[(wq * 2 + qs) * 256 + l16 * 16 + quad * 4] = ol[qs];
    }
    __syncthreads();
    if (wk == 0) {
#pragma unroll
      for (int qs = 0; qs < 2; ++qs)
        ol[qs] += *(const v4f*)&red[(wq * 2 + qs) * 256 + l16 * 16 + quad * 4];
    }
    __syncthreads();
    if (wk == 1) {
#pragma unroll
      for (int qs = 0; qs < 2; ++qs)
#pragma unroll
        for (int nf = 0; nf < 8; ++nf)
          *(v4f*)&red[(((wq * 2 + qs) * 8 + nf) * 256) + l16 * 16 + quad * 4] = o[qs][nf];
    }
    __syncthreads();
    if (wk == 0) {
#pragma unroll
      for (int qs = 0; qs < 2; ++qs) {
        float inv[4];
#pragma unroll
        for (int r = 0; r < 4; ++r) inv[r] = 1.0f / ol[qs][r];
#pragma unroll
        for (int nf = 0; nf < 8; ++nf) {
          v4f osum = o[qs][nf] + *(const v4f*)&red[(((wq * 2 + qs) * 8 + nf) * 256) + l16 * 16 + quad * 4];
#pragma unroll
          for (int r = 0; r < 4; ++r) {
            const int row = qb + qs * 16 + quad * 4 + r;
            ctx[(size_t)(b * 2048 + row) * 2048 + h * 128 + nf * 16 + l16] = f2bf(osum[r] * inv[r]);
          }
        }
      }
    }
  }
}

extern "C" void kernel_launch(void* const* d_in, const int* in_sizes, int n_in,
                              void* d_out, int out_size, void* d_ws, size_t ws_size,
                              hipStream_t stream) {
  const float* x = (const float*)d_in[0];
  const float* Wq = (const float*)d_in[1];
  const float* Wk = (const float*)d_in[2];
  const float* Wv = (const float*)d_in[3];
  const float* Wo = (const float*)d_in[4];
  const float* bo = (const float*)d_in[5];
  float* out = (float*)d_out;
  char* ws = (char*)d_ws;

  // workspace layout (bytes), total 64 MiB; ctx aliases xb
  short* xb    = (short*)(ws);             // 16,777,216  x bf16 [4096][2048]
  short* ctx   = (short*)(ws);             // alias       [4096][2048]
  short* Wqkvt = (short*)(ws + 16777216);  // 12,582,912  [3072 n][2048 k] packed Q|K|V
  short* Wot   = (short*)(ws + 29360128);  //  8,388,608  [2048 n][2048 k]
  short* QKV   = (short*)(ws + 37748736);  // 25,165,824  [4096][3072]
  short* Vtb   = (short*)(ws + 62914560);  //  4,194,304  [b][512][2048] key-permuted

  cast_and_transpose<<<18432, 256, 0, stream>>>(x, xb, Wq, Wk, Wv, Wo, Wqkvt, Wot);

  // QKV: M=4096,N=3072,K=2048 -> 24x32=768 blocks = exactly 3/CU
  gemm_bt2p<1><<<768, 256, 0, stream>>>(xb, Wqkvt, (void*)QKV, nullptr, 3072, 2048, 24, 96);

  transpose_v_perm<<<dim3(16, 64, 2), dim3(32, 8), 0, stream>>>(QKV, Vtb);

  flash_attn4<<<dim3(16, 32), 256, 0, stream>>>(QKV, Vtb, ctx);

  // out: M=4096,N=2048,K=2048 -> 16x32=512 blocks = 2/CU
  gemm_bt2p<0><<<512, 256, 0, stream>>>(ctx, Wot, (void*)out, bo, 2048, 2048, 16, 64);
}

// Round 5
// 279.378 us; speedup vs baseline: 1.1704x; 1.0342x over previous
//
#include <hip/hip_runtime.h>

typedef short v8s __attribute__((ext_vector_type(8)));
typedef float v4f __attribute__((ext_vector_type(4)));

__device__ __forceinline__ short f2bf(float f) {
  union { float f; unsigned u; } v; v.f = f;
  unsigned r = v.u + 0x7FFFu + ((v.u >> 16) & 1u);
  return (short)(r >> 16);
}

// async global->LDS, 16B per lane; LDS dst = wave-uniform base + lane*16
__device__ __forceinline__ void gll16(const short* g, short* l) {
  __builtin_amdgcn_global_load_lds(
      (const __attribute__((address_space(1))) void*)g,
      (__attribute__((address_space(3))) void*)l, 16, 0, 0);
}

// ---------------- merged: x cast (blocks 0..8191) + weight transposes ----------------
__global__ void cast_and_transpose(const float* __restrict__ x, short* __restrict__ xb,
                                   const float* __restrict__ Wq, const float* __restrict__ Wk,
                                   const float* __restrict__ Wv, const float* __restrict__ Wo,
                                   short* __restrict__ Wqkvt, short* __restrict__ Wot) {
  const int tid = threadIdx.x;
  int bid = blockIdx.x;
  if (bid < 8192) {
    int i = bid * 256 + tid;
    float4 v = ((const float4*)x)[i];
    short4 o;
    o.x = f2bf(v.x); o.y = f2bf(v.y); o.z = f2bf(v.z); o.w = f2bf(v.w);
    ((short4*)xb)[i] = o;
    return;
  }
  __shared__ float tile[32][33];
  bid -= 8192;
  const int tx = tid & 31, ty = tid >> 5;
  int bx = bid % 160;
  const int byy = bid / 160;
  const float* src; short* dst; int C, cb;
  if (bx < 64)      { src = Wq; dst = Wqkvt;                        C = 2048; cb = bx; }
  else if (bx < 80) { src = Wk; dst = Wqkvt + (size_t)2048 * 2048;  C = 512;  cb = bx - 64; }
  else if (bx < 96) { src = Wv; dst = Wqkvt + (size_t)2560 * 2048;  C = 512;  cb = bx - 80; }
  else              { src = Wo; dst = Wot;                          C = 2048; cb = bx - 96; }
  const int c0 = cb * 32, r0 = byy * 32;
#pragma unroll
  for (int i = 0; i < 4; ++i)
    tile[ty + 8 * i][tx] = src[(size_t)(r0 + ty + 8 * i) * C + c0 + tx];
  __syncthreads();
#pragma unroll
  for (int i = 0; i < 4; ++i)
    dst[(size_t)(c0 + ty + 8 * i) * 2048 + r0 + tx] = f2bf(tile[tx][ty + 8 * i]);
}

// ---------------- V transpose + key-permute out of packed QKV ----------------
__global__ void transpose_v_perm(const short* __restrict__ qkv, short* __restrict__ out) {
  __shared__ short tile[32][33];
  const int tx = threadIdx.x, ty = threadIdx.y;
  const int c0 = blockIdx.x * 32, r0 = blockIdx.y * 32;
  const int z = blockIdx.z;
#pragma unroll
  for (int i = 0; i < 4; ++i)
    tile[ty + 8 * i][tx] = qkv[(size_t)(z * 2048 + r0 + ty + 8 * i) * 3072 + 2560 + c0 + tx];
  __syncthreads();
#pragma unroll
  for (int i = 0; i < 4; ++i) {
    int k = r0 + tx;
    int pk = (k & ~31) | ((((k >> 2) & 3) * 2 + ((k >> 4) & 1)) * 4) | (k & 3);
    out[(size_t)z * 512 * 2048 + (size_t)(c0 + ty + 8 * i) * 2048 + pk] = tile[tx][ty + 8 * i];
  }
}

// ---------------- GEMM v2p: C[M][N] = A[M][K] @ Bt[N][K]^T (bf16 in) ----------------
// 128x128 tile, BK=32, double-buffered LDS (32 KiB), 2-phase pipeline, XOR chunk
// swizzle, 3 blocks/CU. (Unchanged from round-4 verified version.)
template <int BF16_OUT>
__global__ __launch_bounds__(256, 3) void gemm_bt2p(const short* __restrict__ A,
                                                    const short* __restrict__ Bt,
                                                    void* __restrict__ Cout,
                                                    const float* __restrict__ bias,
                                                    int N, int K, int nbx, int cpx) {
  __shared__ __align__(16) short sm[2 * 8192];  // 2 bufs x (A[128][32] | B[128][32])
  const int tid = threadIdx.x;
  const int w = tid >> 6, lane = tid & 63, quad = lane >> 4, l16 = lane & 15;
  const int wm = (w >> 1) * 64, wn = (w & 1) * 64;
  const int bid = blockIdx.x;
  const int swz = (bid & 7) * cpx + (bid >> 3);
  const int n0 = (swz % nbx) * 128, m0 = (swz / nbx) * 128;
  const int NT = K >> 5;

  const int srow = lane >> 2;
  const int sc = ((lane & 3) ^ ((lane >> 2) & 3) ^ ((lane >> 4) & 3)) * 8;
  const short* Ag = A + (size_t)(m0 + w * 16 + srow) * K + sc;
  const short* Bg = Bt + (size_t)(n0 + w * 16 + srow) * K + sc;
  short* Ad = sm + w * 512 + lane * 8;
  short* Bd = sm + 4096 + w * 512 + lane * 8;
  const size_t rjump = (size_t)64 * K;

  auto stage = [&](int t, int bf_) {
    const int k = t << 5;
    short* ad = Ad + bf_ * 8192;
    short* bd = Bd + bf_ * 8192;
    gll16(Ag + k, ad);
    gll16(Ag + k + rjump, ad + 2048);
    gll16(Bg + k, bd);
    gll16(Bg + k + rjump, bd + 2048);
  };

  const int rsc = (quad ^ (l16 & 3) ^ ((l16 >> 2) & 3)) * 8;
  const short* aBase = sm + (wm + l16) * 32 + rsc;
  const short* bBase = sm + 4096 + (wn + l16) * 32 + rsc;

  v4f acc[4][4] = {};

  stage(0, 0);
  __syncthreads();

  for (int t = 0; t < NT; ++t) {
    if (t + 1 < NT) stage(t + 1, (t + 1) & 1);  // overlaps with this tile's compute
    const int bo_ = (t & 1) * 8192;
    v8s af[4], bf[4];
#pragma unroll
    for (int i = 0; i < 4; ++i) af[i] = *(const v8s*)(aBase + bo_ + i * 512);
#pragma unroll
    for (int i = 0; i < 4; ++i) bf[i] = *(const v8s*)(bBase + bo_ + i * 512);
    __builtin_amdgcn_s_setprio(1);
#pragma unroll
    for (int mi = 0; mi < 4; ++mi)
#pragma unroll
      for (int ni = 0; ni < 4; ++ni)
        acc[mi][ni] = __builtin_amdgcn_mfma_f32_16x16x32_bf16(af[mi], bf[ni], acc[mi][ni], 0, 0, 0);
    __builtin_amdgcn_s_setprio(0);
    if (t + 1 < NT) __syncthreads();  // drains stage(t+1); publishes buf (t+1)&1
  }

#pragma unroll
  for (int mi = 0; mi < 4; ++mi) {
#pragma unroll
    for (int ni = 0; ni < 4; ++ni) {
      const int col = n0 + wn + ni * 16 + l16;
#pragma unroll
      for (int r = 0; r < 4; ++r) {
        const int row = m0 + wm + mi * 16 + quad * 4 + r;
        if (BF16_OUT) {
          ((short*)Cout)[(size_t)row * N + col] = f2bf(acc[mi][ni][r]);
        } else {
          ((float*)Cout)[(size_t)row * N + col] = acc[mi][ni][r] + bias[col];
        }
      }
    }
  }
}

// ---------------- flash attention v6 ----------------
// grid (16, 32), 512-thread blocks (8 waves): paired 64-row q-tiles (qt=bx, 31-bx),
// uniform 33 ktiles. 8 waves as wq(4) x wk(2): each wave owns 16 q-rows x 32 keys
// (qs loop removed vs v5). 512 blocks x 8 waves / 256 CU = 16 waves/CU = 4 waves/SIMD
// (was 2) — LDS 64 KiB double-buffer x 2 blocks = 128 <= 160 KiB; launch_bounds(512,4)
// caps VGPR at 128 (accumulators halved: o[8]+aq[4] ~ 48 regs). Same staging swizzles,
// same P^T->PV key-permute contract, same wk-pair epilogue reduction.
__global__ __launch_bounds__(512, 4) void flash_attn6(const short* __restrict__ QKV,
                                                      const short* __restrict__ Vtb,
                                                      short* __restrict__ ctx) {
  __shared__ __align__(16) short smem[32768];  // 2 x (Ks 8192 + Vs 8192); epilogue overlay
  const int tid = threadIdx.x;
  const int w = tid >> 6, lane = tid & 63, quad = lane >> 4, l16 = lane & 15;
  const int wq = w >> 1, wk = w & 1;
  const int bh = blockIdx.y;
  const int b = bh >> 4, h = bh & 15, g = h >> 2;
  // exp(s*scale) = exp2(s * scale * log2e)
  const float k2e = 0.08838834764831845f * 1.4426950408889634f;
  v8s ones;
#pragma unroll
  for (int i = 0; i < 8; ++i) ones[i] = (short)0x3F80;

  // staging lane roles: wave w stages K rows w*8..+7 and V d-rows w*16..+15
  const int krl = lane >> 4, kcl = lane & 15;   // K: 4 rows x 16 col-chunks per gll16 round
  const int vrl = lane >> 3, vcl = lane & 7;    // V: 8 rows x 8  col-chunks per gll16 round
  const short* Kg0 = QKV + (size_t)(b * 2048 + w * 8 + krl) * 3072 + 2048 + g * 128;
  const short* Vg0 = Vtb + (size_t)(b * 512 + g * 128 + w * 16 + vrl) * 2048 + (vcl ^ (vrl & 7)) * 8;
  short* kd = smem + (w * 8) * 128 + lane * 8;
  short* vd = smem + 8192 + (w * 16) * 64 + lane * 8;

  auto stage = [&](int key0, int bs) {
    const short* kg = Kg0 + (size_t)key0 * 3072;
    const short* vg = Vg0 + key0;
#pragma unroll
    for (int ii = 0; ii < 2; ++ii) {
      const int rl = (w & 1) * 8 + ii * 4 + krl;   // = (staged K row) & 15
      gll16(kg + (size_t)(ii * 4) * 3072 + (kcl ^ rl) * 8, kd + bs * 16384 + ii * 512);
      gll16(vg + (size_t)(ii * 8) * 2048, vd + bs * 16384 + ii * 512);
    }
  };

  float* red = (float*)smem;

#pragma unroll 1
  for (int half = 0; half < 2; ++half) {
    const int qt = half ? (31 - blockIdx.x) : blockIdx.x;
    const int q0 = qt * 64;
    const int qb = q0 + wq * 16;

    // Q fragments: this wave's 16 rows (serve as MFMA B-operand for S^T = K*Q^T)
    v8s aq[4];
    {
      const short* Qp = QKV + (size_t)(b * 2048 + qb + l16) * 3072 + h * 128 + quad * 8;
#pragma unroll
      for (int kk = 0; kk < 4; ++kk) aq[kk] = *(const v8s*)(Qp + kk * 32);
    }
    v4f o[8] = {};
    v4f ol = {};

    __syncthreads();            // protect smem from previous half's epilogue readers
    stage(0, 0);
    const int nk = qt + 1;
#pragma unroll 1
    for (int kt = 0; kt < nk; ++kt) {
      const int key0 = kt << 6;
      __syncthreads();          // drains stage(kt) [vmcnt(0)], orders buffer reuse
      if (kt + 1 < nk) stage((kt + 1) << 6, (kt + 1) & 1);
      const short* Ks = smem + (kt & 1) * 16384;
      const short* Vs = Ks + 8192;
      const int kb = key0 + wk * 32;
      if (kb > qb + 15) continue;  // wave-uniform: fully masked
      // S^T = K @ Q^T for this wave's 32 keys x 16 q
      v4f sf[2] = {};
      __builtin_amdgcn_s_setprio(1);
#pragma unroll
      for (int kfl = 0; kfl < 2; ++kfl)
#pragma unroll
        for (int kk = 0; kk < 4; ++kk) {
          v8s kfr = *(const v8s*)&Ks[((wk * 2 + kfl) * 16 + l16) * 128 + (((kk * 4 + quad) ^ l16) * 8)];
          sf[kfl] = __builtin_amdgcn_mfma_f32_16x16x32_bf16(kfr, aq[kk], sf[kfl], 0, 0, 0);
        }
      __builtin_amdgcn_s_setprio(0);
      // mask + exp + pack P^T C-layout -> PV A-frag (32 keys)
      const bool diag = (kb + 31 > qb);
      const int qg = qb + l16;
      v8s pa;
#pragma unroll
      for (int kfl = 0; kfl < 2; ++kfl)
#pragma unroll
        for (int r = 0; r < 4; ++r) {
          float s = sf[kfl][r];
          if (diag && (kb + kfl * 16 + quad * 4 + r > qg)) s = -1e30f;
          pa[kfl * 4 + r] = f2bf(exp2f(s * k2e));
        }
      // O += P @ V ; l += P @ 1
      __builtin_amdgcn_s_setprio(1);
#pragma unroll
      for (int nf = 0; nf < 8; ++nf) {
        v8s vf = *(const v8s*)&Vs[(nf * 16 + l16) * 64 + (((wk * 4 + quad) ^ (l16 & 7)) * 8)];
        o[nf] = __builtin_amdgcn_mfma_f32_16x16x32_bf16(pa, vf, o[nf], 0, 0, 0);
      }
      ol = __builtin_amdgcn_mfma_f32_16x16x32_bf16(pa, ones, ol, 0, 0, 0);
      __builtin_amdgcn_s_setprio(0);
    }
    __syncthreads();   // all LDS reads of K/V done; smem becomes reduction buffer

    // ---- epilogue: sum o/l across the wk pair, normalize, store ----
    // phase A: l
    if (wk == 1)
      *(v4f*)&red[wq * 256 + l16 * 16 + quad * 4] = ol;
    __syncthreads();
    if (wk == 0)
      ol += *(const v4f*)&red[wq * 256 + l16 * 16 + quad * 4];
    __syncthreads();
    // phase B: o
    if (wk == 1) {
#pragma unroll
      for (int nf = 0; nf < 8; ++nf)
        *(v4f*)&red[(wq * 8 + nf) * 256 + l16 * 16 + quad * 4] = o[nf];
    }
    __syncthreads();
    if (wk == 0) {
      float inv[4];
#pragma unroll
      for (int r = 0; r < 4; ++r) inv[r] = 1.0f / ol[r];
#pragma unroll
      for (int nf = 0; nf < 8; ++nf) {
        v4f osum = o[nf] + *(const v4f*)&red[(wq * 8 + nf) * 256 + l16 * 16 + quad * 4];
#pragma unroll
        for (int r = 0; r < 4; ++r) {
          const int row = qb + quad * 4 + r;
          ctx[(size_t)(b * 2048 + row) * 2048 + h * 128 + nf * 16 + l16] = f2bf(osum[r] * inv[r]);
        }
      }
    }
  }
}

extern "C" void kernel_launch(void* const* d_in, const int* in_sizes, int n_in,
                              void* d_out, int out_size, void* d_ws, size_t ws_size,
                              hipStream_t stream) {
  const float* x = (const float*)d_in[0];
  const float* Wq = (const float*)d_in[1];
  const float* Wk = (const float*)d_in[2];
  const float* Wv = (const float*)d_in[3];
  const float* Wo = (const float*)d_in[4];
  const float* bo = (const float*)d_in[5];
  float* out = (float*)d_out;
  char* ws = (char*)d_ws;

  // workspace layout (bytes), total 64 MiB; ctx aliases xb
  short* xb    = (short*)(ws);             // 16,777,216  x bf16 [4096][2048]
  short* ctx   = (short*)(ws);             // alias       [4096][2048]
  short* Wqkvt = (short*)(ws + 16777216);  // 12,582,912  [3072 n][2048 k] packed Q|K|V
  short* Wot   = (short*)(ws + 29360128);  //  8,388,608  [2048 n][2048 k]
  short* QKV   = (short*)(ws + 37748736);  // 25,165,824  [4096][3072]
  short* Vtb   = (short*)(ws + 62914560);  //  4,194,304  [b][512][2048] key-permuted

  cast_and_transpose<<<18432, 256, 0, stream>>>(x, xb, Wq, Wk, Wv, Wo, Wqkvt, Wot);

  // QKV: M=4096,N=3072,K=2048 -> 24x32=768 blocks = exactly 3/CU
  gemm_bt2p<1><<<768, 256, 0, stream>>>(xb, Wqkvt, (void*)QKV, nullptr, 3072, 2048, 24, 96);

  transpose_v_perm<<<dim3(16, 64, 2), dim3(32, 8), 0, stream>>>(QKV, Vtb);

  flash_attn6<<<dim3(16, 32), 512, 0, stream>>>(QKV, Vtb, ctx);

  // out: M=4096,N=2048,K=2048 -> 16x32=512 blocks = 2/CU
  gemm_bt2p<0><<<512, 256, 0, stream>>>(ctx, Wot, (void*)out, bo, 2048, 2048, 16, 64);
}